// Round 7
// baseline (306.567 us; speedup 1.0000x reference)
//
#include <hip/hip_runtime.h>
#include <hip/hip_bf16.h>
#include <math.h>

#define N_NODES 50000
#define E_EDGES 1600000
#define HF 128          // H*F = 4*32
#define INV_CUTOFF 0.25f
#define ENV_A -36.0f
#define ENV_B 63.0f
#define ENV_C -28.0f

#define GEMM_BLOCKS ((N_NODES + 63) / 64)   // 782: 64 rows per block (16/wave)
#define REC_CAP 72    // slots per node; deg ~ Poisson(32), 7.2 sigma tail

typedef __attribute__((ext_vector_type(8))) short bf16x8;
typedef __attribute__((ext_vector_type(4))) float f32x4;

// round-to-nearest-even fp32 -> bf16 bits
__device__ __forceinline__ unsigned short f2bf(float f) {
  unsigned u = __float_as_uint(f);
  u += 0x7fffu + ((u >> 16) & 1u);
  return (unsigned short)(u >> 16);
}
__device__ __forceinline__ unsigned pack2(float lo, float hi) {
  return (unsigned)f2bf(lo) | ((unsigned)f2bf(hi) << 16);
}
__device__ __forceinline__ float2 up2(unsigned v) {
  return make_float2(__uint_as_float(v << 16), __uint_as_float(v & 0xffff0000u));
}

// ---- forced packed-fp32 ops (VOP3P: all srcs must be 64-bit VGPR pairs) ----
__device__ __forceinline__ float2 pk_add(float2 a, float2 b) {
  float2 d;
  asm("v_pk_add_f32 %0, %1, %2" : "=v"(d) : "v"(a), "v"(b));
  return d;
}
__device__ __forceinline__ float2 pk_fma(float2 a, float2 b, float2 c) {
  float2 d;
  asm("v_pk_fma_f32 %0, %1, %2, %3" : "=v"(d) : "v"(a), "v"(b), "v"(c));
  return d;
}
__device__ __forceinline__ float2 pk_abs(float2 a) {
  float2 d;
  d.x = __uint_as_float(__float_as_uint(a.x) & 0x7fffffffu);
  d.y = __uint_as_float(__float_as_uint(a.y) & 0x7fffffffu);
  return d;
}

// ------- Kernel 0: prep W -> bf16 pre-swizzled + zero counts (fused) --------
__global__ __launch_bounds__(256) void prep_w(
    const float* __restrict__ Ws, const float* __restrict__ Wd,
    unsigned short* __restrict__ wbf, int* __restrict__ counts) {
  const int q = blockIdx.x * 256 + threadIdx.x;   // 65536 threads
  if (q < 4096) {                                  // 4096 16B chunks of W
    const int n = q >> 4, c = q & 15;
    const float* Wp = ((n < 128) ? Ws : Wd) + (size_t)(n & 127) * HF + c * 8;
    const float4 v0 = *(const float4*)Wp;
    const float4 v1 = *(const float4*)(Wp + 4);
    uint4 pk;
    pk.x = pack2(v0.x, v0.y); pk.y = pack2(v0.z, v0.w);
    pk.z = pack2(v1.x, v1.y); pk.w = pack2(v1.z, v1.w);
    *(uint4*)(wbf + (size_t)n * HF + ((c ^ (n & 15)) * 8)) = pk;
  }
  if (q < N_NODES) counts[q] = 0;
}

// ---------------- Kernel 1: feat GEMMs via MFMA bf16, LDS-staged epilogue ----
// (R1-proven version: W staged in LDS once per block, swizzled banking.)
__global__ __launch_bounds__(256) void feat_gemm(
    const float* __restrict__ x, const unsigned short* __restrict__ wbf,
    const float* __restrict__ bs, const float* __restrict__ bd,
    unsigned short* __restrict__ fs, float* __restrict__ fd) {
  __shared__ unsigned short wlds[256 * 128];   // 64 KB: W first, C-stage after

  // linear copy of pre-swizzled bf16 W: 4096 uint4 chunks / 256 thr = 16 iters
  for (int i = threadIdx.x; i < 4096; i += 256)
    ((uint4*)wlds)[i] = ((const uint4*)wbf)[i];

  const int lane = threadIdx.x & 63;
  const int wave = threadIdx.x >> 6;
  const int m = lane & 15;
  const int quad = lane >> 4;
  const int m0 = blockIdx.x * 64 + wave * 16;
  const int row = m0 + m;
  const int rowc = (row < N_NODES) ? row : (N_NODES - 1);  // clamp OOB loads

  // A-frags: x[rowc][kt*32 + quad*8 .. +7], fp32 -> bf16 RNE
  union { bf16x8 v; unsigned u[4]; } af[4];
  #pragma unroll
  for (int kt = 0; kt < 4; kt++) {
    const float* xp = x + (size_t)rowc * HF + kt * 32 + quad * 8;
    const float4 u0 = *(const float4*)xp;
    const float4 u1 = *(const float4*)(xp + 4);
    af[kt].u[0] = pack2(u0.x, u0.y); af[kt].u[1] = pack2(u0.z, u0.w);
    af[kt].u[2] = pack2(u1.x, u1.y); af[kt].u[3] = pack2(u1.z, u1.w);
  }

  __syncthreads();

  float accA[16][4];
  #pragma unroll
  for (int nt = 0; nt < 16; nt++) {
    const int nrow = nt * 16 + m;        // fused output col & W row
    f32x4 acc = {0.f, 0.f, 0.f, 0.f};
    #pragma unroll
    for (int kt = 0; kt < 4; kt++) {
      const int pc = (kt * 4 + quad) ^ m;
      const bf16x8 bf = *(const bf16x8*)(wlds + (size_t)nrow * HF + pc * 8);
      acc = __builtin_amdgcn_mfma_f32_16x16x32_bf16(af[kt].v, bf, acc, 0, 0, 0);
    }
    accA[nt][0] = acc[0]; accA[nt][1] = acc[1];
    accA[nt][2] = acc[2]; accA[nt][3] = acc[3];
  }

  __syncthreads();   // all waves done reading W; reuse LDS as C-stage
  unsigned short* fsS = wlds;                       // bf16 [64][136] = 17408 B
  float* fdS = (float*)(wlds + 64 * 136);           // f32  [64][132] = 33792 B

  const int rl0 = wave * 16 + quad * 4;             // lane's first local row
  #pragma unroll
  for (int nt = 0; nt < 16; nt++) {
    const int col = nt * 16 + m;
    if (col < 128) {
      const float bias = bs[col];
      #pragma unroll
      for (int r = 0; r < 4; r++)
        fsS[(rl0 + r) * 136 + col] = f2bf(accA[nt][r] + bias);
    } else {
      const float bias = bd[col - 128];
      #pragma unroll
      for (int r = 0; r < 4; r++)
        fdS[(rl0 + r) * 132 + (col - 128)] = accA[nt][r] + bias;
    }
  }
  __syncthreads();

  // coalesced copy-out
  for (int c = threadIdx.x; c < 1024; c += 256) {
    const int r = c >> 4, off = (c & 15) * 8;
    const int gr = blockIdx.x * 64 + r;
    if (gr < N_NODES)
      *(uint4*)(fs + (size_t)gr * HF + off) = *(const uint4*)(fsS + r * 136 + off);
  }
  for (int c = threadIdx.x; c < 2048; c += 256) {
    const int r = c >> 5, off = (c & 31) * 4;
    const int gr = blockIdx.x * 64 + r;
    if (gr < N_NODES)
      *(float4*)(fd + (size_t)gr * HF + off) = *(const float4*)(fdS + r * 132 + off);
  }
}

// ---------------- Kernel 2: direct edge scatter (replaces bucketize+scatter) -
// One pass over the edge list: coalesced reads, one global atomicAdd per edge
// on counts[dst] (50K counters, ~32-way mean contention -> parallel across
// addresses at L2), one 4B scatter store into the per-node slot array.
// Edge order within a node is irrelevant (softmax+sum are order-independent).
__global__ __launch_bounds__(256) void edge_scatter(
    const int* __restrict__ dst, const int* __restrict__ src,
    const float* __restrict__ dist,
    int* __restrict__ counts, unsigned* __restrict__ rec) {
  const int i = blockIdx.x * 256 + threadIdx.x;
  if (i >= E_EDGES) return;
  const int d = dst[i];
  float ds = dist[i] * (INV_CUTOFF * 65536.f);
  unsigned dq = (unsigned)(ds + 0.5f);
  if (dq > 65535u) dq = 65535u;
  const unsigned pay = (unsigned)src[i] | (dq << 16);
  const int pos = atomicAdd(&counts[d], 1);
  if (pos < REC_CAP) rec[(size_t)d * REC_CAP + pos] = pay;
}

// ---------------- Kernel 3: per-node aggregation (R1-proven body) ------------
// PReLU via abs-factorization: prelu(c*u) summed against attn =
//   [0.5(1+al)*c] * sum(attn*u) + [0.5(1-al)*|c|] * sum(attn*|u|)
// Packed-fp32 math throughout; compact 4-edge-slot loop (VGPR 36, occ 68%).
__global__ __launch_bounds__(256) void gat_agg(
    const unsigned short* __restrict__ fs, const float* __restrict__ fd,
    const int* __restrict__ counts, const unsigned* __restrict__ rec,
    const float* __restrict__ attn, const float* __restrict__ alpha_p,
    const float* __restrict__ freqs, float* __restrict__ out) {
  const int wave = threadIdx.x >> 6;
  const int lane = threadIdx.x & 63;
  const int node = blockIdx.x * 4 + wave;
  if (node >= N_NODES) return;
  const int eslot = lane >> 4;
  const int h = (lane >> 2) & 3;
  const int j = lane & 3;
  const int fo = (h << 5) + (j << 3);   // h*32 + j*8

  const float* fdp = fd + (size_t)node * HF + fo;
  const float2 f0 = *(const float2*)(fdp + 0);
  const float2 f1 = *(const float2*)(fdp + 2);
  const float2 f2 = *(const float2*)(fdp + 4);
  const float2 f3 = *(const float2*)(fdp + 6);
  const float2 t0 = *(const float2*)(attn + fo + 0);
  const float2 t1 = *(const float2*)(attn + fo + 2);
  const float2 t2 = *(const float2*)(attn + fo + 4);
  const float2 t3 = *(const float2*)(attn + fo + 6);
  const float al = alpha_p[h];
  const float c1 = 0.5f * (1.0f + al);
  const float c2 = 0.5f * (1.0f - al);
  const float fr = freqs[h];

  const int beg = node * REC_CAP;
  int cnt = counts[node];
  cnt = (cnt < REC_CAP) ? cnt : REC_CAP;
  const int end = beg + cnt;

  float l = 0.f;
  float2 A0 = {0.f, 0.f}, A1 = {0.f, 0.f}, A2 = {0.f, 0.f}, A3 = {0.f, 0.f};

  for (int i = beg; i < end; i += 4) {
    const int e = i + eslot;
    const bool valid = (e < end);
    const unsigned r = rec[valid ? e : beg];
    const int s_idx = (int)(r & 0xffffu);
    const float d = (float)(r >> 16) * (1.0f / 65536.0f);   // = dist/CUTOFF
    const uint4 eb = *(const uint4*)(fs + (size_t)s_idx * HF + fo);  // 8 bf16
    const float2 e0 = up2(eb.x);
    const float2 e1 = up2(eb.y);
    const float2 e2 = up2(eb.z);
    const float2 e3 = up2(eb.w);

    // bessel coeff: env(d)*sin(freq*d); env = d + d^7*(A + B d + C d^2)
    const float d2 = d * d;
    const float d4 = d2 * d2;
    const float d7 = d4 * d2 * d;
    const float env = fmaf(d7, fmaf(d, fmaf(d, ENV_C, ENV_B), ENV_A), d);
    const float cf = env * __sinf(fr * d);
    const float k1 = c1 * cf;
    const float k2 = c2 * fabsf(cf);

    // D1 = sum(attn*u), D2 = sum(attn*|u|), u = el + fd
    float2 D1 = {0.f, 0.f}, D2 = {0.f, 0.f};
    float2 u;
    u = pk_add(e0, f0); D1 = pk_fma(u, t0, D1); D2 = pk_fma(pk_abs(u), t0, D2);
    u = pk_add(e1, f1); D1 = pk_fma(u, t1, D1); D2 = pk_fma(pk_abs(u), t1, D2);
    u = pk_add(e2, f2); D1 = pk_fma(u, t2, D1); D2 = pk_fma(pk_abs(u), t2, D2);
    u = pk_add(e3, f3); D1 = pk_fma(u, t3, D1); D2 = pk_fma(pk_abs(u), t3, D2);

    // p = k1*sum(D1) + k2*sum(D2), then reduce over the 4 j-lanes
    float p = fmaf(k1, D1.x + D1.y, k2 * (D2.x + D2.y));
    p += __shfl_xor(p, 1);
    p += __shfl_xor(p, 2);

    const float w = valid ? __expf(p) : 0.f;
    l += w;
    const float2 w2 = {w, w};
    A0 = pk_fma(w2, e0, A0);
    A1 = pk_fma(w2, e1, A1);
    A2 = pk_fma(w2, e2, A2);
    A3 = pk_fma(w2, e3, A3);
  }

  // combine the 4 edge slots (lanes differing in bits 4,5)
  #pragma unroll
  for (int mm = 16; mm < 64; mm <<= 1) {
    l    += __shfl_xor(l, mm);
    A0.x += __shfl_xor(A0.x, mm); A0.y += __shfl_xor(A0.y, mm);
    A1.x += __shfl_xor(A1.x, mm); A1.y += __shfl_xor(A1.y, mm);
    A2.x += __shfl_xor(A2.x, mm); A2.y += __shfl_xor(A2.y, mm);
    A3.x += __shfl_xor(A3.x, mm); A3.y += __shfl_xor(A3.y, mm);
  }

  if (eslot == 0) {
    const float rl = (l > 0.f) ? 1.0f / l : 0.f;
    float* o = out + (size_t)node * HF + fo;
    float4 o0 = {A0.x * rl, A0.y * rl, A1.x * rl, A1.y * rl};
    float4 o1 = {A2.x * rl, A2.y * rl, A3.x * rl, A3.y * rl};
    *(float4*)o = o0;
    *(float4*)(o + 4) = o1;
  }
}

// ---------------- launcher ----------------
extern "C" void kernel_launch(void* const* d_in, const int* in_sizes, int n_in,
                              void* d_out, int out_size, void* d_ws, size_t ws_size,
                              hipStream_t stream) {
  const float* x      = (const float*)d_in[0];
  const float* dist   = (const float*)d_in[1];
  const float* W_src  = (const float*)d_in[2];
  const float* b_src  = (const float*)d_in[3];
  const float* W_dst  = (const float*)d_in[4];
  const float* b_dst  = (const float*)d_in[5];
  const float* attn   = (const float*)d_in[6];
  const float* alpha  = (const float*)d_in[7];
  const float* freqs  = (const float*)d_in[8];
  const int*   src    = (const int*)d_in[9];
  const int*   dst    = (const int*)d_in[10];
  float* out = (float*)d_out;

  char* w = (char*)d_ws;
  size_t off = 0;
  auto alloc = [&](size_t bytes) -> void* {
    void* p = w + off;
    off += (bytes + 255) & ~(size_t)255;
    return p;
  };
  unsigned short* feat_src = (unsigned short*)alloc((size_t)N_NODES * HF * 2);
  float*          feat_dst = (float*)alloc((size_t)N_NODES * HF * 4);
  unsigned short* wbf      = (unsigned short*)alloc((size_t)256 * HF * 2);
  int*            counts   = (int*)alloc((size_t)N_NODES * 4);
  unsigned*       rec      = (unsigned*)alloc((size_t)N_NODES * REC_CAP * 4);

  prep_w<<<256, 256, 0, stream>>>(W_src, W_dst, wbf, counts);

  feat_gemm<<<GEMM_BLOCKS, 256, 0, stream>>>(x, wbf, b_src, b_dst, feat_src, feat_dst);

  edge_scatter<<<(E_EDGES + 255) / 256, 256, 0, stream>>>(dst, src, dist, counts, rec);

  gat_agg<<<(N_NODES + 3) / 4, 256, 0, stream>>>(
      feat_src, feat_dst, counts, rec, attn, alpha, freqs, out);
}

// Round 8
// 248.538 us; speedup vs baseline: 1.2335x; 1.2335x over previous
//
#include <hip/hip_runtime.h>
#include <hip/hip_bf16.h>
#include <math.h>

#define N_NODES 50000
#define E_EDGES 1600000
#define HF 128          // H*F = 4*32
#define INV_CUTOFF 0.25f
#define ENV_A -36.0f
#define ENV_B 63.0f
#define ENV_C -28.0f

#define GEMM_BLOCKS ((N_NODES + 63) / 64)   // 782: 64 rows per block (16/wave)
#define REC_CAP 72    // slots per node; deg ~ Poisson(32), 7.2 sigma tail
#define NBUCK 196     // buckets of 256 nodes: bucket = dst >> 8
#define BUCK_CAP 8960 // mean 8192, sd 90 -> 8.5 sigma
#define EPB 6250      // edges per bucketize block (256 blocks exact)
#define SPLIT 4       // blocks per bucket in bucket_scatter
#define LCAP 32       // per-split per-node slot cap: Binom(deg<=72, 1/4) tail >6 sigma

typedef __attribute__((ext_vector_type(8))) short bf16x8;
typedef __attribute__((ext_vector_type(4))) float f32x4;

// round-to-nearest-even fp32 -> bf16 bits
__device__ __forceinline__ unsigned short f2bf(float f) {
  unsigned u = __float_as_uint(f);
  u += 0x7fffu + ((u >> 16) & 1u);
  return (unsigned short)(u >> 16);
}
__device__ __forceinline__ unsigned pack2(float lo, float hi) {
  return (unsigned)f2bf(lo) | ((unsigned)f2bf(hi) << 16);
}
__device__ __forceinline__ float2 up2(unsigned v) {
  return make_float2(__uint_as_float(v << 16), __uint_as_float(v & 0xffff0000u));
}

// ---- forced packed-fp32 ops (VOP3P: all srcs must be 64-bit VGPR pairs) ----
__device__ __forceinline__ float2 pk_add(float2 a, float2 b) {
  float2 d;
  asm("v_pk_add_f32 %0, %1, %2" : "=v"(d) : "v"(a), "v"(b));
  return d;
}
__device__ __forceinline__ float2 pk_fma(float2 a, float2 b, float2 c) {
  float2 d;
  asm("v_pk_fma_f32 %0, %1, %2, %3" : "=v"(d) : "v"(a), "v"(b), "v"(c));
  return d;
}
__device__ __forceinline__ float2 pk_abs(float2 a) {
  float2 d;
  d.x = __uint_as_float(__float_as_uint(a.x) & 0x7fffffffu);
  d.y = __uint_as_float(__float_as_uint(a.y) & 0x7fffffffu);
  return d;
}

// ---------------- Kernel 1: feat GEMMs via MFMA bf16, LDS-staged epilogue ----
// W converted fp32->bf16 + bank-swizzled during the LDS staging loop (prep_w
// kernel eliminated; 128KB fp32 W is L2-resident across all 782 blocks).
__global__ __launch_bounds__(256) void feat_gemm(
    const float* __restrict__ x, const float* __restrict__ Ws,
    const float* __restrict__ Wd,
    const float* __restrict__ bs, const float* __restrict__ bd,
    unsigned short* __restrict__ fs, float* __restrict__ fd) {
  __shared__ unsigned short wlds[256 * 128];   // 64 KB: W first, C-stage after

  // stage W: 4096 16B chunks / 256 thr = 16 iters; convert + swizzle in-flight
  for (int i = threadIdx.x; i < 4096; i += 256) {
    const int n = i >> 4, c = i & 15;
    const float* Wp = ((n < 128) ? Ws : Wd) + (size_t)(n & 127) * HF + c * 8;
    const float4 v0 = *(const float4*)Wp;
    const float4 v1 = *(const float4*)(Wp + 4);
    uint4 pk;
    pk.x = pack2(v0.x, v0.y); pk.y = pack2(v0.z, v0.w);
    pk.z = pack2(v1.x, v1.y); pk.w = pack2(v1.z, v1.w);
    ((uint4*)wlds)[n * 16 + (c ^ (n & 15))] = pk;
  }

  const int lane = threadIdx.x & 63;
  const int wave = threadIdx.x >> 6;
  const int m = lane & 15;
  const int quad = lane >> 4;
  const int m0 = blockIdx.x * 64 + wave * 16;
  const int row = m0 + m;
  const int rowc = (row < N_NODES) ? row : (N_NODES - 1);  // clamp OOB loads

  // A-frags: x[rowc][kt*32 + quad*8 .. +7], fp32 -> bf16 RNE
  union { bf16x8 v; unsigned u[4]; } af[4];
  #pragma unroll
  for (int kt = 0; kt < 4; kt++) {
    const float* xp = x + (size_t)rowc * HF + kt * 32 + quad * 8;
    const float4 u0 = *(const float4*)xp;
    const float4 u1 = *(const float4*)(xp + 4);
    af[kt].u[0] = pack2(u0.x, u0.y); af[kt].u[1] = pack2(u0.z, u0.w);
    af[kt].u[2] = pack2(u1.x, u1.y); af[kt].u[3] = pack2(u1.z, u1.w);
  }

  __syncthreads();

  float accA[16][4];
  #pragma unroll
  for (int nt = 0; nt < 16; nt++) {
    const int nrow = nt * 16 + m;        // fused output col & W row
    f32x4 acc = {0.f, 0.f, 0.f, 0.f};
    #pragma unroll
    for (int kt = 0; kt < 4; kt++) {
      const int pc = (kt * 4 + quad) ^ m;
      const bf16x8 bf = *(const bf16x8*)(wlds + (size_t)nrow * HF + pc * 8);
      acc = __builtin_amdgcn_mfma_f32_16x16x32_bf16(af[kt].v, bf, acc, 0, 0, 0);
    }
    accA[nt][0] = acc[0]; accA[nt][1] = acc[1];
    accA[nt][2] = acc[2]; accA[nt][3] = acc[3];
  }

  __syncthreads();   // all waves done reading W; reuse LDS as C-stage
  unsigned short* fsS = wlds;                       // bf16 [64][136] = 17408 B
  float* fdS = (float*)(wlds + 64 * 136);           // f32  [64][132] = 33792 B

  const int rl0 = wave * 16 + quad * 4;             // lane's first local row
  #pragma unroll
  for (int nt = 0; nt < 16; nt++) {
    const int col = nt * 16 + m;
    if (col < 128) {
      const float bias = bs[col];
      #pragma unroll
      for (int r = 0; r < 4; r++)
        fsS[(rl0 + r) * 136 + col] = f2bf(accA[nt][r] + bias);
    } else {
      const float bias = bd[col - 128];
      #pragma unroll
      for (int r = 0; r < 4; r++)
        fdS[(rl0 + r) * 132 + (col - 128)] = accA[nt][r] + bias;
    }
  }
  __syncthreads();

  // coalesced copy-out
  for (int c = threadIdx.x; c < 1024; c += 256) {
    const int r = c >> 4, off = (c & 15) * 8;
    const int gr = blockIdx.x * 64 + r;
    if (gr < N_NODES)
      *(uint4*)(fs + (size_t)gr * HF + off) = *(const uint4*)(fsS + r * 136 + off);
  }
  for (int c = threadIdx.x; c < 2048; c += 256) {
    const int r = c >> 5, off = (c & 31) * 4;
    const int gr = blockIdx.x * 64 + r;
    if (gr < N_NODES)
      *(float4*)(fd + (size_t)gr * HF + off) = *(const float4*)(fdS + r * 132 + off);
  }
}

// ---------------- Kernel 2: bucketize via LDS grouping + coalesced flush -----
__global__ __launch_bounds__(256) void bucketize(
    const int* __restrict__ dst, const int* __restrict__ src,
    const float* __restrict__ dist,
    int* __restrict__ bcursor, unsigned* __restrict__ bb_pay,
    unsigned char* __restrict__ bb_loc) {
  __shared__ unsigned pay_s[EPB];          // 25000 B
  __shared__ unsigned char bkt_s[EPB];     // 6250 B
  __shared__ unsigned char loc_s[EPB];     // 6250 B
  __shared__ int hist[NBUCK], loff[NBUCK], base[NBUCK], cur[NBUCK];
  for (int t = threadIdx.x; t < NBUCK; t += 256) { hist[t] = 0; cur[t] = 0; }
  __syncthreads();
  const int lo = blockIdx.x * EPB;   // 256*6250 == E_EDGES exactly
  for (int k = threadIdx.x; k < EPB; k += 256)
    atomicAdd(&hist[dst[lo + k] >> 8], 1);
  __syncthreads();
  if (threadIdx.x == 0) {
    int run = 0;
    for (int j = 0; j < NBUCK; j++) { loff[j] = run; run += hist[j]; }
  }
  __syncthreads();
  for (int t = threadIdx.x; t < NBUCK; t += 256)
    base[t] = atomicAdd(&bcursor[t], hist[t]);
  __syncthreads();
  for (int k = threadIdx.x; k < EPB; k += 256) {
    const int d = dst[lo + k];
    const int b = d >> 8;
    float ds = dist[lo + k] * (INV_CUTOFF * 65536.f);
    unsigned dq = (unsigned)(ds + 0.5f);
    if (dq > 65535u) dq = 65535u;
    const int s = loff[b] + atomicAdd(&cur[b], 1);
    pay_s[s] = (unsigned)src[lo + k] | (dq << 16);
    bkt_s[s] = (unsigned char)b;
    loc_s[s] = (unsigned char)(d & 255);
  }
  __syncthreads();
  // flush: consecutive s within a bucket -> consecutive dest (coalesced runs)
  for (int s = threadIdx.x; s < EPB; s += 256) {
    const int b = bkt_s[s];
    const int dest = base[b] + (s - loff[b]);
    if (dest < BUCK_CAP) {
      bb_pay[(size_t)b * BUCK_CAP + dest] = pay_s[s];
      bb_loc[(size_t)b * BUCK_CAP + dest] = loc_s[s];
    }
  }
}

// ---------------- Kernel 3: split-bucket rank + small-LDS stage, run flush ---
// Each bucket is processed by SPLIT blocks over disjoint edge ranges; edge
// order within a node is irrelevant (softmax+sum are order-independent), so
// global ranks come from one atomicAdd(&counts[node], cl) per node per block.
__global__ __launch_bounds__(256) void bucket_scatter(
    const int* __restrict__ bcursor, const unsigned* __restrict__ bb_pay,
    const unsigned char* __restrict__ bb_loc,
    int* __restrict__ counts, unsigned* __restrict__ rec) {
  __shared__ int cnt[256];
  __shared__ unsigned recS[256 * LCAP];   // 32 KB
  cnt[threadIdx.x] = 0;
  __syncthreads();
  const int b = blockIdx.x / SPLIT;
  const int q = blockIdx.x - b * SPLIT;
  const int total = min(bcursor[b], BUCK_CAP);
  const int lo = (total * q) / SPLIT;
  const int hi = (total * (q + 1)) / SPLIT;
  const size_t base = (size_t)b * BUCK_CAP;
  for (int i = lo + threadIdx.x; i < hi; i += 256) {
    const unsigned pay = bb_pay[base + i];
    const int local = bb_loc[base + i];
    const int r = atomicAdd(&cnt[local], 1);
    if (r < LCAP) recS[local * LCAP + r] = pay;
  }
  __syncthreads();
  const int node = (b << 8) + (int)threadIdx.x;
  if (node < N_NODES) {
    const int cl = min(cnt[threadIdx.x], LCAP);
    if (cl > 0) {
      const int gbase = atomicAdd(&counts[node], cl);
      unsigned* dstp = rec + (size_t)node * REC_CAP;
      const unsigned* srcp = recS + threadIdx.x * LCAP;
      for (int k = 0; k < cl; k++) {
        const int pos = gbase + k;
        if (pos < REC_CAP) dstp[pos] = srcp[k];
      }
    }
  }
}

// ---------------- Kernel 4: per-node aggregation (R1-proven body) ------------
// PReLU via abs-factorization: prelu(c*u) summed against attn =
//   [0.5(1+al)*c] * sum(attn*u) + [0.5(1-al)*|c|] * sum(attn*|u|)
// Packed-fp32 math throughout; compact 4-edge-slot loop (VGPR 36, occ 68%).
__global__ __launch_bounds__(256) void gat_agg(
    const unsigned short* __restrict__ fs, const float* __restrict__ fd,
    const int* __restrict__ counts, const unsigned* __restrict__ rec,
    const float* __restrict__ attn, const float* __restrict__ alpha_p,
    const float* __restrict__ freqs, float* __restrict__ out) {
  const int wave = threadIdx.x >> 6;
  const int lane = threadIdx.x & 63;
  const int node = blockIdx.x * 4 + wave;
  if (node >= N_NODES) return;
  const int eslot = lane >> 4;
  const int h = (lane >> 2) & 3;
  const int j = lane & 3;
  const int fo = (h << 5) + (j << 3);   // h*32 + j*8

  const float* fdp = fd + (size_t)node * HF + fo;
  const float2 f0 = *(const float2*)(fdp + 0);
  const float2 f1 = *(const float2*)(fdp + 2);
  const float2 f2 = *(const float2*)(fdp + 4);
  const float2 f3 = *(const float2*)(fdp + 6);
  const float2 t0 = *(const float2*)(attn + fo + 0);
  const float2 t1 = *(const float2*)(attn + fo + 2);
  const float2 t2 = *(const float2*)(attn + fo + 4);
  const float2 t3 = *(const float2*)(attn + fo + 6);
  const float al = alpha_p[h];
  const float c1 = 0.5f * (1.0f + al);
  const float c2 = 0.5f * (1.0f - al);
  const float fr = freqs[h];

  const int beg = node * REC_CAP;
  int cnt = counts[node];
  cnt = (cnt < REC_CAP) ? cnt : REC_CAP;
  const int end = beg + cnt;

  float l = 0.f;
  float2 A0 = {0.f, 0.f}, A1 = {0.f, 0.f}, A2 = {0.f, 0.f}, A3 = {0.f, 0.f};

  for (int i = beg; i < end; i += 4) {
    const int e = i + eslot;
    const bool valid = (e < end);
    const unsigned r = rec[valid ? e : beg];
    const int s_idx = (int)(r & 0xffffu);
    const float d = (float)(r >> 16) * (1.0f / 65536.0f);   // = dist/CUTOFF
    const uint4 eb = *(const uint4*)(fs + (size_t)s_idx * HF + fo);  // 8 bf16
    const float2 e0 = up2(eb.x);
    const float2 e1 = up2(eb.y);
    const float2 e2 = up2(eb.z);
    const float2 e3 = up2(eb.w);

    // bessel coeff: env(d)*sin(freq*d); env = d + d^7*(A + B d + C d^2)
    const float d2 = d * d;
    const float d4 = d2 * d2;
    const float d7 = d4 * d2 * d;
    const float env = fmaf(d7, fmaf(d, fmaf(d, ENV_C, ENV_B), ENV_A), d);
    const float cf = env * __sinf(fr * d);
    const float k1 = c1 * cf;
    const float k2 = c2 * fabsf(cf);

    // D1 = sum(attn*u), D2 = sum(attn*|u|), u = el + fd
    float2 D1 = {0.f, 0.f}, D2 = {0.f, 0.f};
    float2 u;
    u = pk_add(e0, f0); D1 = pk_fma(u, t0, D1); D2 = pk_fma(pk_abs(u), t0, D2);
    u = pk_add(e1, f1); D1 = pk_fma(u, t1, D1); D2 = pk_fma(pk_abs(u), t1, D2);
    u = pk_add(e2, f2); D1 = pk_fma(u, t2, D1); D2 = pk_fma(pk_abs(u), t2, D2);
    u = pk_add(e3, f3); D1 = pk_fma(u, t3, D1); D2 = pk_fma(pk_abs(u), t3, D2);

    // p = k1*sum(D1) + k2*sum(D2), then reduce over the 4 j-lanes
    float p = fmaf(k1, D1.x + D1.y, k2 * (D2.x + D2.y));
    p += __shfl_xor(p, 1);
    p += __shfl_xor(p, 2);

    const float w = valid ? __expf(p) : 0.f;
    l += w;
    const float2 w2 = {w, w};
    A0 = pk_fma(w2, e0, A0);
    A1 = pk_fma(w2, e1, A1);
    A2 = pk_fma(w2, e2, A2);
    A3 = pk_fma(w2, e3, A3);
  }

  // combine the 4 edge slots (lanes differing in bits 4,5)
  #pragma unroll
  for (int mm = 16; mm < 64; mm <<= 1) {
    l    += __shfl_xor(l, mm);
    A0.x += __shfl_xor(A0.x, mm); A0.y += __shfl_xor(A0.y, mm);
    A1.x += __shfl_xor(A1.x, mm); A1.y += __shfl_xor(A1.y, mm);
    A2.x += __shfl_xor(A2.x, mm); A2.y += __shfl_xor(A2.y, mm);
    A3.x += __shfl_xor(A3.x, mm); A3.y += __shfl_xor(A3.y, mm);
  }

  if (eslot == 0) {
    const float rl = (l > 0.f) ? 1.0f / l : 0.f;
    float* o = out + (size_t)node * HF + fo;
    float4 o0 = {A0.x * rl, A0.y * rl, A1.x * rl, A1.y * rl};
    float4 o1 = {A2.x * rl, A2.y * rl, A3.x * rl, A3.y * rl};
    *(float4*)o = o0;
    *(float4*)(o + 4) = o1;
  }
}

// ---------------- launcher ----------------
extern "C" void kernel_launch(void* const* d_in, const int* in_sizes, int n_in,
                              void* d_out, int out_size, void* d_ws, size_t ws_size,
                              hipStream_t stream) {
  const float* x      = (const float*)d_in[0];
  const float* dist   = (const float*)d_in[1];
  const float* W_src  = (const float*)d_in[2];
  const float* b_src  = (const float*)d_in[3];
  const float* W_dst  = (const float*)d_in[4];
  const float* b_dst  = (const float*)d_in[5];
  const float* attn   = (const float*)d_in[6];
  const float* alpha  = (const float*)d_in[7];
  const float* freqs  = (const float*)d_in[8];
  const int*   src    = (const int*)d_in[9];
  const int*   dst    = (const int*)d_in[10];
  float* out = (float*)d_out;

  char* w = (char*)d_ws;
  size_t off = 0;
  auto alloc = [&](size_t bytes) -> void* {
    void* p = w + off;
    off += (bytes + 255) & ~(size_t)255;
    return p;
  };
  unsigned short* feat_src = (unsigned short*)alloc((size_t)N_NODES * HF * 2);
  float*          feat_dst = (float*)alloc((size_t)N_NODES * HF * 4);
  // counts and bcursor adjacent -> one memset clears both
  int*            counts   = (int*)alloc((size_t)N_NODES * 4);
  int*            bcursor  = (int*)alloc((size_t)NBUCK * 4);
  unsigned*       bb_pay   = (unsigned*)alloc((size_t)NBUCK * BUCK_CAP * 4);
  unsigned char*  bb_loc   = (unsigned char*)alloc((size_t)NBUCK * BUCK_CAP);
  unsigned*       rec      = (unsigned*)alloc((size_t)N_NODES * REC_CAP * 4);

  const size_t counts_pad = ((size_t)N_NODES * 4 + 255) & ~(size_t)255;
  hipMemsetAsync(counts, 0, counts_pad + (size_t)NBUCK * 4, stream);

  feat_gemm<<<GEMM_BLOCKS, 256, 0, stream>>>(x, W_src, W_dst, b_src, b_dst,
                                             feat_src, feat_dst);

  bucketize<<<256, 256, 0, stream>>>(dst, src, dist, bcursor, bb_pay, bb_loc);

  bucket_scatter<<<NBUCK * SPLIT, 256, 0, stream>>>(bcursor, bb_pay, bb_loc, counts, rec);

  gat_agg<<<(N_NODES + 3) / 4, 256, 0, stream>>>(
      feat_src, feat_dst, counts, rec, attn, alpha, freqs, out);
}

// Round 9
// 244.019 us; speedup vs baseline: 1.2563x; 1.0185x over previous
//
#include <hip/hip_runtime.h>
#include <hip/hip_bf16.h>
#include <math.h>

#define N_NODES 50000
#define E_EDGES 1600000
#define HF 128          // H*F = 4*32
#define INV_CUTOFF 0.25f
#define ENV_A -36.0f
#define ENV_B 63.0f
#define ENV_C -28.0f

#define GEMM_BLOCKS ((N_NODES + 63) / 64)   // 782: 64 rows per block (16/wave)
#define REC_CAP 72    // slots per node; deg ~ Poisson(32), 7.2 sigma tail
#define NBUCK 196     // buckets of 256 nodes: bucket = dst >> 8
#define BUCK_CAP 8960 // mean 8192, sd 90 -> 8.5 sigma
#define EPB 6250      // edges per bucketize block (256 blocks exact)
#define SPLIT 4       // blocks per bucket in bucket_scatter
#define LCAP 32       // per-split per-node slot cap: Binom(deg<=72, 1/4) tail >6 sigma

typedef __attribute__((ext_vector_type(8))) short bf16x8;
typedef __attribute__((ext_vector_type(4))) float f32x4;

// round-to-nearest-even fp32 -> bf16 bits
__device__ __forceinline__ unsigned short f2bf(float f) {
  unsigned u = __float_as_uint(f);
  u += 0x7fffu + ((u >> 16) & 1u);
  return (unsigned short)(u >> 16);
}
__device__ __forceinline__ unsigned pack2(float lo, float hi) {
  return (unsigned)f2bf(lo) | ((unsigned)f2bf(hi) << 16);
}
__device__ __forceinline__ float2 up2(unsigned v) {
  return make_float2(__uint_as_float(v << 16), __uint_as_float(v & 0xffff0000u));
}

// ---- plain float2 helpers (NO inline asm): compiler is free to SLP-pack to
// v_pk_* or emit scalar VOP3 with free abs()/neg() input modifiers.
__device__ __forceinline__ float2 p2add(float2 a, float2 b) {
  return make_float2(a.x + b.x, a.y + b.y);
}
__device__ __forceinline__ float2 p2fma(float2 a, float2 b, float2 c) {
  return make_float2(fmaf(a.x, b.x, c.x), fmaf(a.y, b.y, c.y));
}
__device__ __forceinline__ float2 p2abs(float2 a) {
  return make_float2(fabsf(a.x), fabsf(a.y));
}
__device__ __forceinline__ float2 p2fmas(float s, float2 b, float2 c) {
  return make_float2(fmaf(s, b.x, c.x), fmaf(s, b.y, c.y));
}

// ---------------- Kernel 1: phase1 = feat GEMM blocks ∥ bucketize blocks -----
// blocks [0, GEMM_BLOCKS): MFMA feature GEMM (W converted+swizzled in staging).
// blocks [GEMM_BLOCKS, GEMM_BLOCKS+256): bucketize. Disjoint data, different
// pipes (MFMA/LDS vs atomics/HBM) -> co-resident overlap in one dispatch.
__global__ __launch_bounds__(256) void phase1(
    const float* __restrict__ x, const float* __restrict__ Ws,
    const float* __restrict__ Wd,
    const float* __restrict__ bs, const float* __restrict__ bd,
    unsigned short* __restrict__ fs, float* __restrict__ fd,
    const int* __restrict__ dst, const int* __restrict__ src,
    const float* __restrict__ dist,
    int* __restrict__ bcursor, unsigned* __restrict__ bb_pay,
    unsigned char* __restrict__ bb_loc) {
  __shared__ __align__(16) char smem[65536];   // shared by both paths

  if (blockIdx.x < GEMM_BLOCKS) {
    // ================= GEMM path =================
    unsigned short* wlds = (unsigned short*)smem;   // 64 KB: W, then C-stage

    // stage W: 4096 16B chunks / 256 thr; convert fp32->bf16 + swizzle
    for (int i = threadIdx.x; i < 4096; i += 256) {
      const int n = i >> 4, c = i & 15;
      const float* Wp = ((n < 128) ? Ws : Wd) + (size_t)(n & 127) * HF + c * 8;
      const float4 v0 = *(const float4*)Wp;
      const float4 v1 = *(const float4*)(Wp + 4);
      uint4 pk;
      pk.x = pack2(v0.x, v0.y); pk.y = pack2(v0.z, v0.w);
      pk.z = pack2(v1.x, v1.y); pk.w = pack2(v1.z, v1.w);
      ((uint4*)wlds)[n * 16 + (c ^ (n & 15))] = pk;
    }

    const int lane = threadIdx.x & 63;
    const int wave = threadIdx.x >> 6;
    const int m = lane & 15;
    const int quad = lane >> 4;
    const int row = blockIdx.x * 64 + wave * 16 + m;
    const int rowc = (row < N_NODES) ? row : (N_NODES - 1);

    union { bf16x8 v; unsigned u[4]; } af[4];
    #pragma unroll
    for (int kt = 0; kt < 4; kt++) {
      const float* xp = x + (size_t)rowc * HF + kt * 32 + quad * 8;
      const float4 u0 = *(const float4*)xp;
      const float4 u1 = *(const float4*)(xp + 4);
      af[kt].u[0] = pack2(u0.x, u0.y); af[kt].u[1] = pack2(u0.z, u0.w);
      af[kt].u[2] = pack2(u1.x, u1.y); af[kt].u[3] = pack2(u1.z, u1.w);
    }

    __syncthreads();

    float accA[16][4];
    #pragma unroll
    for (int nt = 0; nt < 16; nt++) {
      const int nrow = nt * 16 + m;
      f32x4 acc = {0.f, 0.f, 0.f, 0.f};
      #pragma unroll
      for (int kt = 0; kt < 4; kt++) {
        const int pc = (kt * 4 + quad) ^ m;
        const bf16x8 bf = *(const bf16x8*)(wlds + (size_t)nrow * HF + pc * 8);
        acc = __builtin_amdgcn_mfma_f32_16x16x32_bf16(af[kt].v, bf, acc, 0, 0, 0);
      }
      accA[nt][0] = acc[0]; accA[nt][1] = acc[1];
      accA[nt][2] = acc[2]; accA[nt][3] = acc[3];
    }

    __syncthreads();   // reuse LDS as C-stage
    unsigned short* fsS = wlds;                       // bf16 [64][136]
    float* fdS = (float*)(wlds + 64 * 136);           // f32  [64][132]

    const int rl0 = wave * 16 + quad * 4;
    #pragma unroll
    for (int nt = 0; nt < 16; nt++) {
      const int col = nt * 16 + m;
      if (col < 128) {
        const float bias = bs[col];
        #pragma unroll
        for (int r = 0; r < 4; r++)
          fsS[(rl0 + r) * 136 + col] = f2bf(accA[nt][r] + bias);
      } else {
        const float bias = bd[col - 128];
        #pragma unroll
        for (int r = 0; r < 4; r++)
          fdS[(rl0 + r) * 132 + (col - 128)] = accA[nt][r] + bias;
      }
    }
    __syncthreads();

    for (int c = threadIdx.x; c < 1024; c += 256) {
      const int r = c >> 4, off = (c & 15) * 8;
      const int gr = blockIdx.x * 64 + r;
      if (gr < N_NODES)
        *(uint4*)(fs + (size_t)gr * HF + off) = *(const uint4*)(fsS + r * 136 + off);
    }
    for (int c = threadIdx.x; c < 2048; c += 256) {
      const int r = c >> 5, off = (c & 31) * 4;
      const int gr = blockIdx.x * 64 + r;
      if (gr < N_NODES)
        *(float4*)(fd + (size_t)gr * HF + off) = *(const float4*)(fdS + r * 132 + off);
    }
  } else {
    // ================= bucketize path =================
    unsigned* pay_s      = (unsigned*)smem;                    // 25000 B
    unsigned char* bkt_s = (unsigned char*)(smem + 25000);     // 6250 B
    unsigned char* loc_s = (unsigned char*)(smem + 31250);     // 6250 B
    int* hist = (int*)(smem + 37504);                          // 784 B each
    int* loff = hist + NBUCK;
    int* base = loff + NBUCK;
    int* cur  = base + NBUCK;

    const int bb = blockIdx.x - GEMM_BLOCKS;   // 0..255
    for (int t = threadIdx.x; t < NBUCK; t += 256) { hist[t] = 0; cur[t] = 0; }
    __syncthreads();
    const int lo = bb * EPB;   // 256*6250 == E_EDGES exactly
    for (int k = threadIdx.x; k < EPB; k += 256)
      atomicAdd(&hist[dst[lo + k] >> 8], 1);
    __syncthreads();
    if (threadIdx.x == 0) {
      int run = 0;
      for (int j = 0; j < NBUCK; j++) { loff[j] = run; run += hist[j]; }
    }
    __syncthreads();
    for (int t = threadIdx.x; t < NBUCK; t += 256)
      base[t] = atomicAdd(&bcursor[t], hist[t]);
    __syncthreads();
    for (int k = threadIdx.x; k < EPB; k += 256) {
      const int d = dst[lo + k];
      const int b = d >> 8;
      float ds = dist[lo + k] * (INV_CUTOFF * 65536.f);
      unsigned dq = (unsigned)(ds + 0.5f);
      if (dq > 65535u) dq = 65535u;
      const int s = loff[b] + atomicAdd(&cur[b], 1);
      pay_s[s] = (unsigned)src[lo + k] | (dq << 16);
      bkt_s[s] = (unsigned char)b;
      loc_s[s] = (unsigned char)(d & 255);
    }
    __syncthreads();
    for (int s = threadIdx.x; s < EPB; s += 256) {
      const int b = bkt_s[s];
      const int dest = base[b] + (s - loff[b]);
      if (dest < BUCK_CAP) {
        bb_pay[(size_t)b * BUCK_CAP + dest] = pay_s[s];
        bb_loc[(size_t)b * BUCK_CAP + dest] = loc_s[s];
      }
    }
  }
}

// ---------------- Kernel 2: split-bucket rank + small-LDS stage, run flush ---
__global__ __launch_bounds__(256) void bucket_scatter(
    const int* __restrict__ bcursor, const unsigned* __restrict__ bb_pay,
    const unsigned char* __restrict__ bb_loc,
    int* __restrict__ counts, unsigned* __restrict__ rec) {
  __shared__ int cnt[256];
  __shared__ unsigned recS[256 * LCAP];   // 32 KB
  cnt[threadIdx.x] = 0;
  __syncthreads();
  const int b = blockIdx.x / SPLIT;
  const int q = blockIdx.x - b * SPLIT;
  const int total = min(bcursor[b], BUCK_CAP);
  const int lo = (total * q) / SPLIT;
  const int hi = (total * (q + 1)) / SPLIT;
  const size_t base = (size_t)b * BUCK_CAP;
  for (int i = lo + threadIdx.x; i < hi; i += 256) {
    const unsigned pay = bb_pay[base + i];
    const int local = bb_loc[base + i];
    const int r = atomicAdd(&cnt[local], 1);
    if (r < LCAP) recS[local * LCAP + r] = pay;
  }
  __syncthreads();
  const int node = (b << 8) + (int)threadIdx.x;
  if (node < N_NODES) {
    const int cl = min(cnt[threadIdx.x], LCAP);
    if (cl > 0) {
      const int gbase = atomicAdd(&counts[node], cl);
      unsigned* dstp = rec + (size_t)node * REC_CAP;
      const unsigned* srcp = recS + threadIdx.x * LCAP;
      for (int k = 0; k < cl; k++) {
        const int pos = gbase + k;
        if (pos < REC_CAP) dstp[pos] = srcp[k];
      }
    }
  }
}

// ---------------- Kernel 3: per-node aggregation (R1 structure, NO asm) ------
// PReLU abs-factorization: sum(attn*prelu(c*u)) =
//   [0.5(1+al)*c]*sum(attn*u) + [0.5(1-al)*|c|]*sum(attn*|u|)
// Plain float math: VOP3 fma gets abs() as a free input modifier; compiler
// may SLP-pack to v_pk_* without asm-copy overhead.
__global__ __launch_bounds__(256) void gat_agg(
    const unsigned short* __restrict__ fs, const float* __restrict__ fd,
    const int* __restrict__ counts, const unsigned* __restrict__ rec,
    const float* __restrict__ attn, const float* __restrict__ alpha_p,
    const float* __restrict__ freqs, float* __restrict__ out) {
  const int wave = threadIdx.x >> 6;
  const int lane = threadIdx.x & 63;
  const int node = blockIdx.x * 4 + wave;
  if (node >= N_NODES) return;
  const int eslot = lane >> 4;
  const int h = (lane >> 2) & 3;
  const int j = lane & 3;
  const int fo = (h << 5) + (j << 3);   // h*32 + j*8

  const float* fdp = fd + (size_t)node * HF + fo;
  const float2 f0 = *(const float2*)(fdp + 0);
  const float2 f1 = *(const float2*)(fdp + 2);
  const float2 f2 = *(const float2*)(fdp + 4);
  const float2 f3 = *(const float2*)(fdp + 6);
  const float2 t0 = *(const float2*)(attn + fo + 0);
  const float2 t1 = *(const float2*)(attn + fo + 2);
  const float2 t2 = *(const float2*)(attn + fo + 4);
  const float2 t3 = *(const float2*)(attn + fo + 6);
  const float al = alpha_p[h];
  const float c1 = 0.5f * (1.0f + al);
  const float c2 = 0.5f * (1.0f - al);
  const float fr = freqs[h];

  const int beg = node * REC_CAP;
  int cnt = counts[node];
  cnt = (cnt < REC_CAP) ? cnt : REC_CAP;
  const int end = beg + cnt;
  const unsigned short* fsp = fs + fo;

  float l = 0.f;
  float2 A0 = {0.f, 0.f}, A1 = {0.f, 0.f}, A2 = {0.f, 0.f}, A3 = {0.f, 0.f};

  for (int i = beg; i < end; i += 4) {
    const int e = i + eslot;
    const bool valid = (e < end);
    const unsigned r = rec[valid ? e : beg];
    const int s_idx = (int)(r & 0xffffu);
    const float d = (float)(r >> 16) * (1.0f / 65536.0f);   // = dist/CUTOFF
    const uint4 eb = *(const uint4*)(fsp + ((size_t)s_idx << 7));  // 8 bf16
    const float2 e0 = up2(eb.x);
    const float2 e1 = up2(eb.y);
    const float2 e2 = up2(eb.z);
    const float2 e3 = up2(eb.w);

    // bessel coeff: env(d)*sin(freq*d); env = d + d^7*(A + B d + C d^2)
    const float d2 = d * d;
    const float d4 = d2 * d2;
    const float d7 = d4 * d2 * d;
    const float env = fmaf(d7, fmaf(d, fmaf(d, ENV_C, ENV_B), ENV_A), d);
    const float cf = env * __sinf(fr * d);
    const float k1 = c1 * cf;
    const float k2 = c2 * fabsf(cf);

    // D1 = sum(attn*u), D2 = sum(attn*|u|), u = el + fd
    float2 D1 = {0.f, 0.f}, D2 = {0.f, 0.f};
    float2 u;
    u = p2add(e0, f0); D1 = p2fma(u, t0, D1); D2 = p2fma(p2abs(u), t0, D2);
    u = p2add(e1, f1); D1 = p2fma(u, t1, D1); D2 = p2fma(p2abs(u), t1, D2);
    u = p2add(e2, f2); D1 = p2fma(u, t2, D1); D2 = p2fma(p2abs(u), t2, D2);
    u = p2add(e3, f3); D1 = p2fma(u, t3, D1); D2 = p2fma(p2abs(u), t3, D2);

    // p = k1*sum(D1) + k2*sum(D2), then reduce over the 4 j-lanes
    float p = fmaf(k1, D1.x + D1.y, k2 * (D2.x + D2.y));
    p += __shfl_xor(p, 1);
    p += __shfl_xor(p, 2);

    const float w = valid ? __expf(p) : 0.f;
    l += w;
    A0 = p2fmas(w, e0, A0);
    A1 = p2fmas(w, e1, A1);
    A2 = p2fmas(w, e2, A2);
    A3 = p2fmas(w, e3, A3);
  }

  // combine the 4 edge slots (lanes differing in bits 4,5)
  #pragma unroll
  for (int mm = 16; mm < 64; mm <<= 1) {
    l    += __shfl_xor(l, mm);
    A0.x += __shfl_xor(A0.x, mm); A0.y += __shfl_xor(A0.y, mm);
    A1.x += __shfl_xor(A1.x, mm); A1.y += __shfl_xor(A1.y, mm);
    A2.x += __shfl_xor(A2.x, mm); A2.y += __shfl_xor(A2.y, mm);
    A3.x += __shfl_xor(A3.x, mm); A3.y += __shfl_xor(A3.y, mm);
  }

  if (eslot == 0) {
    const float rl = (l > 0.f) ? 1.0f / l : 0.f;
    float* o = out + (size_t)node * HF + fo;
    float4 o0 = {A0.x * rl, A0.y * rl, A1.x * rl, A1.y * rl};
    float4 o1 = {A2.x * rl, A2.y * rl, A3.x * rl, A3.y * rl};
    *(float4*)o = o0;
    *(float4*)(o + 4) = o1;
  }
}

// ---------------- launcher ----------------
extern "C" void kernel_launch(void* const* d_in, const int* in_sizes, int n_in,
                              void* d_out, int out_size, void* d_ws, size_t ws_size,
                              hipStream_t stream) {
  const float* x      = (const float*)d_in[0];
  const float* dist   = (const float*)d_in[1];
  const float* W_src  = (const float*)d_in[2];
  const float* b_src  = (const float*)d_in[3];
  const float* W_dst  = (const float*)d_in[4];
  const float* b_dst  = (const float*)d_in[5];
  const float* attn   = (const float*)d_in[6];
  const float* alpha  = (const float*)d_in[7];
  const float* freqs  = (const float*)d_in[8];
  const int*   src    = (const int*)d_in[9];
  const int*   dst    = (const int*)d_in[10];
  float* out = (float*)d_out;

  char* w = (char*)d_ws;
  size_t off = 0;
  auto alloc = [&](size_t bytes) -> void* {
    void* p = w + off;
    off += (bytes + 255) & ~(size_t)255;
    return p;
  };
  unsigned short* feat_src = (unsigned short*)alloc((size_t)N_NODES * HF * 2);
  float*          feat_dst = (float*)alloc((size_t)N_NODES * HF * 4);
  // counts and bcursor adjacent -> one memset clears both
  int*            counts   = (int*)alloc((size_t)N_NODES * 4);
  int*            bcursor  = (int*)alloc((size_t)NBUCK * 4);
  unsigned*       bb_pay   = (unsigned*)alloc((size_t)NBUCK * BUCK_CAP * 4);
  unsigned char*  bb_loc   = (unsigned char*)alloc((size_t)NBUCK * BUCK_CAP);
  unsigned*       rec      = (unsigned*)alloc((size_t)N_NODES * REC_CAP * 4);

  const size_t counts_pad = ((size_t)N_NODES * 4 + 255) & ~(size_t)255;
  hipMemsetAsync(counts, 0, counts_pad + (size_t)NBUCK * 4, stream);

  phase1<<<GEMM_BLOCKS + 256, 256, 0, stream>>>(
      x, W_src, W_dst, b_src, b_dst, feat_src, feat_dst,
      dst, src, dist, bcursor, bb_pay, bb_loc);

  bucket_scatter<<<NBUCK * SPLIT, 256, 0, stream>>>(bcursor, bb_pay, bb_loc, counts, rec);

  gat_agg<<<(N_NODES + 3) / 4, 256, 0, stream>>>(
      feat_src, feat_dst, counts, rec, attn, alpha, freqs, out);
}